// Round 2
// baseline (181.781 us; speedup 1.0000x reference)
//
#include <hip/hip_runtime.h>
#include <hip/hip_bf16.h>

// out[b,n] = sum_k cos(x[b,k] * mean(phases[k,:])) * W[k,n]
// B = 4096, K = 1024, N = 4096, NQ = 12. All fp32 in/out.
//
// Strategy: no fp32 MFMA on CDNA4 -> emulate fp32 GEMM via bf16 hi/lo split
// (3-term: hh + hl + lh) on mfma_f32_16x16x32_bf16.
// Producers write operands in a tiled+XOR-swizzled layout so the GEMM can use
// linear global_load_lds (dwordx4) and conflict-reduced ds_read_b128.

#define K_DIM 1024
#define N_DIM 4096
#define B_DIM 4096
#define NQ 12

typedef __attribute__((ext_vector_type(8))) __bf16 bf16x8;
typedef __attribute__((ext_vector_type(4))) float f32x4;

__device__ inline ushort f2bh(float f) {
    // fp32 -> bf16 round-to-nearest-even (values are finite, no NaN handling needed)
    unsigned u = __float_as_uint(f);
    return (ushort)((u + 0x7fffu + ((u >> 16) & 1u)) >> 16);
}
__device__ inline float bh2f(ushort h) {
    return __uint_as_float(((unsigned)h) << 16);
}

// ---------------- phase mean ----------------
__global__ void pm_kernel(const float* __restrict__ phases, float* __restrict__ pm) {
    int j = blockIdx.x * 256 + threadIdx.x;
    if (j < K_DIM) {
        float s = 0.f;
#pragma unroll
        for (int q = 0; q < NQ; ++q) s += phases[j * NQ + q];
        pm[j] = s * (1.0f / NQ);
    }
}

// ---------------- A producer: coef = cos(x*pm), hi/lo split, tiled+swizzled ----------------
// Tile layout: tile(tm, kt) = 8192 bytes at ((tm*32)+kt)*8192; element (r,kk):
//   byte = (r*64 + kk*2) ^ ((r&7)<<4)
__global__ void asplit_kernel(const float* __restrict__ x, const float* __restrict__ pm,
                              char* __restrict__ Ah, char* __restrict__ Al) {
    int i = blockIdx.x * 256 + threadIdx.x;   // one thread per 4 consecutive k
    int row = i >> 8;                          // 0..4095   (256 threads per row)
    int k0  = (i & 255) << 2;                  // 0..1020
    float4 xv = *(const float4*)(x + ((size_t)row << 10) + k0);
    float4 pv = *(const float4*)(pm + k0);
    float c0 = cosf(xv.x * pv.x);
    float c1 = cosf(xv.y * pv.y);
    float c2 = cosf(xv.z * pv.z);
    float c3 = cosf(xv.w * pv.w);
    ushort h0 = f2bh(c0), h1 = f2bh(c1), h2 = f2bh(c2), h3 = f2bh(c3);
    ushort l0 = f2bh(c0 - bh2f(h0));
    ushort l1 = f2bh(c1 - bh2f(h1));
    ushort l2 = f2bh(c2 - bh2f(h2));
    ushort l3 = f2bh(c3 - bh2f(h3));

    int tm = row >> 7, kt = k0 >> 5;
    int r = row & 127, kk = k0 & 31;
    size_t tileBase = ((size_t)tm * 32 + (size_t)kt) * 8192;
    int addr = ((r << 6) + (kk << 1)) ^ ((r & 7) << 4);   // 8-byte aligned
    *(ushort4*)(Ah + tileBase + addr) = make_ushort4(h0, h1, h2, h3);
    *(ushort4*)(Al + tileBase + addr) = make_ushort4(l0, l1, l2, l3);
}

// ---------------- W producer: transpose [K][N] -> [N][K], hi/lo split, tiled+swizzled ----------------
__global__ void wsplit_kernel(const float* __restrict__ W,
                              char* __restrict__ Wh, char* __restrict__ Wl) {
    __shared__ float tile[32][33];
    int n0 = blockIdx.x * 32, k0 = blockIdx.y * 32;
    int tx = threadIdx.x, ty = threadIdx.y;
#pragma unroll
    for (int rr = 0; rr < 4; ++rr) {
        int kk = ty + rr * 8;
        tile[kk][tx] = W[(size_t)(k0 + kk) * N_DIM + n0 + tx];   // coalesced in n
    }
    __syncthreads();
    size_t tileBase = ((size_t)(n0 >> 7) * 32 + (size_t)blockIdx.y) * 8192;
#pragma unroll
    for (int rr = 0; rr < 4; ++rr) {
        int nn = ty + rr * 8;            // local out row (n)
        int r  = (n0 & 127) + nn;        // row within 128-row tile
        float v = tile[tx][nn];          // = W[k0+tx][n0+nn]; stride-33 read, conflict-free
        ushort hh = f2bh(v);
        ushort ll = f2bh(v - bh2f(hh));
        int addr = ((r << 6) + (tx << 1)) ^ ((r & 7) << 4);
        *(ushort*)(Wh + tileBase + addr) = hh;
        *(ushort*)(Wl + tileBase + addr) = ll;
    }
}

// ---------------- GEMM: 128x128 tile, BK=32, 4 waves, bf16x3 MFMA ----------------
#define GLL16(g, l)                                                           \
    __builtin_amdgcn_global_load_lds(                                         \
        (const __attribute__((address_space(1))) void*)(g),                   \
        (__attribute__((address_space(3))) void*)(l), 16, 0, 0)

__global__ __launch_bounds__(256, 2) void gemm_kernel(
        const char* __restrict__ Ah, const char* __restrict__ Al,
        const char* __restrict__ Bh, const char* __restrict__ Bl,
        float* __restrict__ C) {
    __shared__ char lds[32768];   // 4 x 8KB: Ah, Al, Bh, Bl tile images (swizzled)
    const int tid  = threadIdx.x;
    const int lane = tid & 63;
    const int wid  = tid >> 6;
    const int wr = wid >> 1, wc = wid & 1;       // 2x2 waves -> 64x64 out each
    const int fr   = lane & 15;                  // fragment row/col
    const int colb = (lane >> 4) << 4;           // byte offset of this lane's 8-bf16 k-group

    const char* pAh = Ah + (size_t)blockIdx.y * 32 * 8192;
    const char* pAl = Al + (size_t)blockIdx.y * 32 * 8192;
    const char* pBh = Bh + (size_t)blockIdx.x * 32 * 8192;
    const char* pBl = Bl + (size_t)blockIdx.x * 32 * 8192;

    int aAddr[4], bAddr[4];
#pragma unroll
    for (int m = 0; m < 4; ++m) {
        int r = wr * 64 + m * 16 + fr;
        aAddr[m] = ((r << 6) + colb) ^ ((r & 7) << 4);
    }
#pragma unroll
    for (int n = 0; n < 4; ++n) {
        int r = wc * 64 + n * 16 + fr;
        bAddr[n] = ((r << 6) + colb) ^ ((r & 7) << 4);
    }

    const int idx0 = tid << 4;          // 0..4080, 16B per thread
    const int idx1 = idx0 + 4096;

    f32x4 acc[4][4];
#pragma unroll
    for (int m = 0; m < 4; ++m)
#pragma unroll
        for (int n = 0; n < 4; ++n)
            acc[m][n] = (f32x4){0.f, 0.f, 0.f, 0.f};

    for (int kt = 0; kt < K_DIM / 32; ++kt) {
        // stage 4 swizzled tile images: linear 8KB copies, global_load_lds x16B
        GLL16(pAh + idx0, lds + idx0);
        GLL16(pAh + idx1, lds + idx1);
        GLL16(pAl + idx0, lds + 8192 + idx0);
        GLL16(pAl + idx1, lds + 8192 + idx1);
        GLL16(pBh + idx0, lds + 16384 + idx0);
        GLL16(pBh + idx1, lds + 16384 + idx1);
        GLL16(pBl + idx0, lds + 24576 + idx0);
        GLL16(pBl + idx1, lds + 24576 + idx1);
        pAh += 8192; pAl += 8192; pBh += 8192; pBl += 8192;
        __syncthreads();   // drains vmcnt -> tiles resident

        bf16x8 aH[4], aL[4], bH[4], bL[4];
#pragma unroll
        for (int m = 0; m < 4; ++m) {
            aH[m] = *(const bf16x8*)(lds + aAddr[m]);
            aL[m] = *(const bf16x8*)(lds + 8192 + aAddr[m]);
        }
#pragma unroll
        for (int n = 0; n < 4; ++n) {
            bH[n] = *(const bf16x8*)(lds + 16384 + bAddr[n]);
            bL[n] = *(const bf16x8*)(lds + 24576 + bAddr[n]);
        }
#pragma unroll
        for (int m = 0; m < 4; ++m)
#pragma unroll
            for (int n = 0; n < 4; ++n) {
                acc[m][n] = __builtin_amdgcn_mfma_f32_16x16x32_bf16(aH[m], bH[n], acc[m][n], 0, 0, 0);
                acc[m][n] = __builtin_amdgcn_mfma_f32_16x16x32_bf16(aH[m], bL[n], acc[m][n], 0, 0, 0);
                acc[m][n] = __builtin_amdgcn_mfma_f32_16x16x32_bf16(aL[m], bH[n], acc[m][n], 0, 0, 0);
            }
        __syncthreads();   // compute done before next stage overwrites
    }

    // epilogue: C/D layout col = lane&15, row = (lane>>4)*4 + j  (m91-verified)
    const int crow0 = blockIdx.y * 128 + wr * 64 + ((lane >> 4) << 2);
    const int ccol0 = blockIdx.x * 128 + wc * 64 + fr;
#pragma unroll
    for (int m = 0; m < 4; ++m)
#pragma unroll
        for (int n = 0; n < 4; ++n) {
            size_t base = (size_t)(crow0 + m * 16) * N_DIM + (size_t)(ccol0 + n * 16);
#pragma unroll
            for (int j = 0; j < 4; ++j)
                C[base + (size_t)j * N_DIM] = acc[m][n][j];
        }
}

extern "C" void kernel_launch(void* const* d_in, const int* in_sizes, int n_in,
                              void* d_out, int out_size, void* d_ws, size_t ws_size,
                              hipStream_t stream) {
    const float* x      = (const float*)d_in[0];   // [4096,1024]
    const float* W      = (const float*)d_in[1];   // [1024,4096]
    const float* phases = (const float*)d_in[2];   // [1024,12]
    float* out = (float*)d_out;                    // [4096,4096] f32

    char* ws = (char*)d_ws;
    float* pm = (float*)ws;                               // 4 KB
    char* Ah = ws + 65536;                                // 8 MB each
    char* Al = Ah + (size_t)8 * 1024 * 1024;
    char* Bh = Al + (size_t)8 * 1024 * 1024;
    char* Bl = Bh + (size_t)8 * 1024 * 1024;
    // total ws use: 64 KB + 32 MB

    pm_kernel<<<4, 256, 0, stream>>>(phases, pm);
    asplit_kernel<<<(B_DIM * (K_DIM / 4)) / 256, 256, 0, stream>>>(x, pm, Ah, Al);
    wsplit_kernel<<<dim3(N_DIM / 32, K_DIM / 32), dim3(32, 8), 0, stream>>>(W, Bh, Bl);
    gemm_kernel<<<dim3(N_DIM / 128, B_DIM / 128), 256, 0, stream>>>(Ah, Al, Bh, Bl, out);
}

// Round 3
// 152.446 us; speedup vs baseline: 1.1924x; 1.1924x over previous
//
#include <hip/hip_runtime.h>
#include <hip/hip_bf16.h>

// out[b,n] = sum_k cos(x[b,k] * mean(phases[k,:])) * W[k,n]
// B = 4096, K = 1024, N = 4096, NQ = 12. All fp32 in/out.
//
// Round 3: 2-term f16 split-GEMM (was 3-term bf16).
//   A = cos coefs split into f16 hi + f16 lo (22-bit effective significand).
//   B = W as single f16 (2^-12 rel quantization -> max out err ~0.013 << 0.5 tol).
//   out = Ah*B + Al*B on mfma_f32_16x16x32_f16.  33% less MFMA work, 25% less staging.
// BK=64 per stage (32 barriers instead of 64). Producers write tiled+XOR-swizzled
// f16 layout with 16B stores; GEMM stages via linear global_load_lds dwordx4.

#define K_DIM 1024
#define N_DIM 4096
#define B_DIM 4096
#define NQ 12

typedef __attribute__((ext_vector_type(8))) _Float16 f16x8;
typedef __attribute__((ext_vector_type(4))) float f32x4;

// Tile layout (both A and B^T): tile = 128 rows x 64 k of f16 = 16384 bytes.
// tile(trow, kt) at ((trow*16)+kt)*16384. Element (r, kk) at byte
//   ((r<<7) + (kk<<1)) ^ ((r&7)<<4)          (bijective: upper-triangular XOR)

// ---------------- phase mean ----------------
__global__ void pm_kernel(const float* __restrict__ phases, float* __restrict__ pm) {
    int j = blockIdx.x * 256 + threadIdx.x;
    if (j < K_DIM) {
        float s = 0.f;
#pragma unroll
        for (int q = 0; q < NQ; ++q) s += phases[j * NQ + q];
        pm[j] = s * (1.0f / NQ);
    }
}

// ---------------- A producer: coef = cos(x*pm), f16 hi/lo, tiled+swizzled ----------------
__global__ void asplit_kernel(const float* __restrict__ x, const float* __restrict__ pm,
                              char* __restrict__ Ah, char* __restrict__ Al) {
    int i = blockIdx.x * 256 + threadIdx.x;    // one thread per 8 consecutive k
    int row = i >> 7;                          // 0..4095  (128 threads per row)
    int k0  = (i & 127) << 3;                  // 0..1016
    const float* xp = x + ((size_t)row << 10) + k0;
    float4 xa = *(const float4*)xp;
    float4 xb = *(const float4*)(xp + 4);
    float4 pa = *(const float4*)(pm + k0);
    float4 pb = *(const float4*)(pm + k0 + 4);
    float c[8];
    c[0] = __cosf(xa.x * pa.x); c[1] = __cosf(xa.y * pa.y);
    c[2] = __cosf(xa.z * pa.z); c[3] = __cosf(xa.w * pa.w);
    c[4] = __cosf(xb.x * pb.x); c[5] = __cosf(xb.y * pb.y);
    c[6] = __cosf(xb.z * pb.z); c[7] = __cosf(xb.w * pb.w);
    f16x8 hv, lv;
#pragma unroll
    for (int j = 0; j < 8; ++j) {
        _Float16 h = (_Float16)c[j];
        hv[j] = h;
        lv[j] = (_Float16)(c[j] - (float)h);
    }
    int tm = row >> 7, kt = k0 >> 6;
    int r = row & 127, kk = k0 & 63;
    size_t base = ((size_t)tm * 16 + (size_t)kt) * 16384;
    int addr = ((r << 7) + (kk << 1)) ^ ((r & 7) << 4);   // 16B aligned
    *(f16x8*)(Ah + base + addr) = hv;
    *(f16x8*)(Al + base + addr) = lv;
}

// ---------------- W producer: transpose [K][N] -> [N][K] f16, tiled+swizzled ----------------
__global__ void wsplit_kernel(const float* __restrict__ W, char* __restrict__ Bf) {
    __shared__ float t[64][65];
    int n0 = blockIdx.x * 64, k0 = blockIdx.y * 64;
    int tid = threadIdx.x;
#pragma unroll
    for (int p = 0; p < 16; ++p) {
        int lin = p * 256 + tid;
        int kk = lin >> 6, nn = lin & 63;
        t[kk][nn] = W[(size_t)(k0 + kk) * N_DIM + n0 + nn];   // coalesced in n
    }
    __syncthreads();
    size_t base = ((size_t)(n0 >> 7) * 16 + (size_t)blockIdx.y) * 16384;
#pragma unroll
    for (int p2 = 0; p2 < 2; ++p2) {
        int w = p2 * 256 + tid;
        int nn = w >> 3, oct = w & 7;       // 64 n x 8 k-octets
        int r = (n0 & 127) + nn;
        f16x8 hv;
#pragma unroll
        for (int j = 0; j < 8; ++j) hv[j] = (_Float16)t[oct * 8 + j][nn];
        int addr = ((r << 7) + (oct << 4)) ^ ((r & 7) << 4);
        *(f16x8*)(Bf + base + addr) = hv;   // 16B store; wave covers 8 rows x 128B
    }
}

// ---------------- GEMM: 128x128 tile, BK=64, 4 waves, f16 2-term ----------------
#define GLL16(g, l)                                                           \
    __builtin_amdgcn_global_load_lds(                                         \
        (const __attribute__((address_space(1))) void*)(g),                   \
        (__attribute__((address_space(3))) void*)(l), 16, 0, 0)

__global__ __launch_bounds__(256, 2) void gemm_kernel(
        const char* __restrict__ Ah, const char* __restrict__ Al,
        const char* __restrict__ Bf, float* __restrict__ C) {
    __shared__ char lds[49152];   // Ah @0, Al @16384, B @32768 (swizzled tile images)
    const int tid  = threadIdx.x;
    const int lane = tid & 63;
    const int wid  = tid >> 6;
    const int wr = wid >> 1, wc = wid & 1;       // 2x2 waves -> 64x64 out each
    const int fr   = lane & 15;
    const int colb = (lane >> 4) << 4;           // byte offset of lane's 8-f16 k-group

    const char* pAh = Ah + (size_t)blockIdx.y * 16 * 16384;
    const char* pAl = Al + (size_t)blockIdx.y * 16 * 16384;
    const char* pBf = Bf + (size_t)blockIdx.x * 16 * 16384;

    int aAddr[4][2], bAddr[4][2];
#pragma unroll
    for (int m = 0; m < 4; ++m) {
        int r = wr * 64 + m * 16 + fr;
#pragma unroll
        for (int kh = 0; kh < 2; ++kh)
            aAddr[m][kh] = ((r << 7) + kh * 64 + colb) ^ ((r & 7) << 4);
    }
#pragma unroll
    for (int n = 0; n < 4; ++n) {
        int r = wc * 64 + n * 16 + fr;
#pragma unroll
        for (int kh = 0; kh < 2; ++kh)
            bAddr[n][kh] = ((r << 7) + kh * 64 + colb) ^ ((r & 7) << 4);
    }

    f32x4 acc[4][4];
#pragma unroll
    for (int m = 0; m < 4; ++m)
#pragma unroll
        for (int n = 0; n < 4; ++n)
            acc[m][n] = (f32x4){0.f, 0.f, 0.f, 0.f};

    for (int kt = 0; kt < K_DIM / 64; ++kt) {
        // stage 3 x 16KB swizzled tile images, linear copies
#pragma unroll
        for (int p = 0; p < 4; ++p) {
            int off = p * 4096 + (tid << 4);
            GLL16(pAh + off, lds + off);
            GLL16(pAl + off, lds + 16384 + off);
            GLL16(pBf + off, lds + 32768 + off);
        }
        pAh += 16384; pAl += 16384; pBf += 16384;
        __syncthreads();   // drains vmcnt -> tiles resident

#pragma unroll
        for (int kh = 0; kh < 2; ++kh) {
            f16x8 aH[4], aL[4], bF[4];
#pragma unroll
            for (int m = 0; m < 4; ++m) {
                aH[m] = *(const f16x8*)(lds + aAddr[m][kh]);
                aL[m] = *(const f16x8*)(lds + 16384 + aAddr[m][kh]);
            }
#pragma unroll
            for (int n = 0; n < 4; ++n)
                bF[n] = *(const f16x8*)(lds + 32768 + bAddr[n][kh]);
#pragma unroll
            for (int m = 0; m < 4; ++m)
#pragma unroll
                for (int n = 0; n < 4; ++n) {
                    acc[m][n] = __builtin_amdgcn_mfma_f32_16x16x32_f16(aH[m], bF[n], acc[m][n], 0, 0, 0);
                    acc[m][n] = __builtin_amdgcn_mfma_f32_16x16x32_f16(aL[m], bF[n], acc[m][n], 0, 0, 0);
                }
        }
        __syncthreads();   // compute done before next stage overwrites
    }

    // epilogue: C/D layout col = lane&15, row = (lane>>4)*4 + j  (m91-verified)
    const int crow0 = blockIdx.y * 128 + wr * 64 + ((lane >> 4) << 2);
    const int ccol0 = blockIdx.x * 128 + wc * 64 + fr;
#pragma unroll
    for (int m = 0; m < 4; ++m)
#pragma unroll
        for (int n = 0; n < 4; ++n) {
            size_t base = (size_t)(crow0 + m * 16) * N_DIM + (size_t)(ccol0 + n * 16);
#pragma unroll
            for (int j = 0; j < 4; ++j)
                C[base + (size_t)j * N_DIM] = acc[m][n][j];
        }
}

extern "C" void kernel_launch(void* const* d_in, const int* in_sizes, int n_in,
                              void* d_out, int out_size, void* d_ws, size_t ws_size,
                              hipStream_t stream) {
    const float* x      = (const float*)d_in[0];   // [4096,1024]
    const float* W      = (const float*)d_in[1];   // [1024,4096]
    const float* phases = (const float*)d_in[2];   // [1024,12]
    float* out = (float*)d_out;                    // [4096,4096] f32

    char* ws = (char*)d_ws;
    float* pm = (float*)ws;                               // 4 KB
    char* Ah = ws + 65536;                                // 8 MB each
    char* Al = Ah + (size_t)8 * 1024 * 1024;
    char* Bf = Al + (size_t)8 * 1024 * 1024;
    // total ws use: 64 KB + 24 MB

    pm_kernel<<<4, 256, 0, stream>>>(phases, pm);
    asplit_kernel<<<(B_DIM * (K_DIM / 8)) / 256, 256, 0, stream>>>(x, pm, Ah, Al);
    wsplit_kernel<<<dim3(N_DIM / 64, K_DIM / 64), 256, 0, stream>>>(W, Bf);
    gemm_kernel<<<dim3(N_DIM / 128, B_DIM / 128), 256, 0, stream>>>(Ah, Al, Bf, out);
}

// Round 4
// 135.118 us; speedup vs baseline: 1.3453x; 1.1282x over previous
//
#include <hip/hip_runtime.h>
#include <hip/hip_bf16.h>

// out[b,n] = sum_k cos(x[b,k] * mean(phases[k,:])) * W[k,n]
// B = 4096, K = 1024, N = 4096, NQ = 12. All fp32 in/out.
//
// Round 4: single-term f16 GEMM (error ~0.044 max << 0.5 tol) on a
// deep-pipelined structure: 256x256 block, 8 waves (2Mx4N, 128x64/wave),
// BK=32, TRIPLE-buffered LDS (96 KB), prefetch depth 2, counted
// s_waitcnt vmcnt(4) (never 0 in loop), 1 barrier/K-tile, setprio around
// MFMA, XCD-aware block swizzle. Producers write tiled+XOR-swizzled f16
// (256 rows x 32 k = 16 KB tiles) so GEMM stages with linear global_load_lds.

#define K_DIM 1024
#define N_DIM 4096
#define B_DIM 4096
#define NQ 12

typedef __attribute__((ext_vector_type(8))) _Float16 f16x8;
typedef __attribute__((ext_vector_type(4))) float f32x4;

// Tile: 256 rows x 32 k f16 = 16384 B. tile(tr, kt) at ((tr*32)+kt)*16384.
// Element (r, kk) at byte ((r<<6) + (kk<<1)) ^ ((r&7)<<4)   (bijective XOR)

// ---------------- phase mean ----------------
__global__ void pm_kernel(const float* __restrict__ phases, float* __restrict__ pm) {
    int j = blockIdx.x * 256 + threadIdx.x;
    if (j < K_DIM) {
        float s = 0.f;
#pragma unroll
        for (int q = 0; q < NQ; ++q) s += phases[j * NQ + q];
        pm[j] = s * (1.0f / NQ);
    }
}

// ---------------- A producer: coef = cos(x*pm) -> f16, tiled+swizzled ----------------
__global__ void asplit_kernel(const float* __restrict__ x, const float* __restrict__ pm,
                              char* __restrict__ Ah) {
    int i = blockIdx.x * 256 + threadIdx.x;    // one thread per 8 consecutive k
    int row = i >> 7;                          // 0..4095  (128 threads per row)
    int k0  = (i & 127) << 3;                  // 0..1016
    const float* xp = x + ((size_t)row << 10) + k0;
    float4 xa = *(const float4*)xp;
    float4 xb = *(const float4*)(xp + 4);
    float4 pa = *(const float4*)(pm + k0);
    float4 pb = *(const float4*)(pm + k0 + 4);
    f16x8 hv;
    hv[0] = (_Float16)__cosf(xa.x * pa.x); hv[1] = (_Float16)__cosf(xa.y * pa.y);
    hv[2] = (_Float16)__cosf(xa.z * pa.z); hv[3] = (_Float16)__cosf(xa.w * pa.w);
    hv[4] = (_Float16)__cosf(xb.x * pb.x); hv[5] = (_Float16)__cosf(xb.y * pb.y);
    hv[6] = (_Float16)__cosf(xb.z * pb.z); hv[7] = (_Float16)__cosf(xb.w * pb.w);
    int tm = row >> 8, kt = k0 >> 5;
    int r = row & 255, kk = k0 & 31;
    size_t base = ((size_t)tm * 32 + (size_t)kt) * 16384;
    int addr = ((r << 6) + (kk << 1)) ^ ((r & 7) << 4);   // 16B aligned
    *(f16x8*)(Ah + base + addr) = hv;
}

// ---------------- W producer: transpose [K][N] -> [N][K] f16, tiled+swizzled ----------------
__global__ void wsplit_kernel(const float* __restrict__ W, char* __restrict__ Bf) {
    __shared__ float t[64][65];
    int n0 = blockIdx.x * 64, k0 = blockIdx.y * 64;
    int tid = threadIdx.x;
#pragma unroll
    for (int p = 0; p < 16; ++p) {
        int lin = p * 256 + tid;
        int kk = lin >> 6, nn = lin & 63;
        t[kk][nn] = W[(size_t)(k0 + kk) * N_DIM + n0 + nn];   // coalesced in n
    }
    __syncthreads();
    int tn = n0 >> 8;
#pragma unroll
    for (int p2 = 0; p2 < 2; ++p2) {
        int w = p2 * 256 + tid;
        int nn = w >> 3, oct = w & 7;       // 64 n x 8 k-octets (of 64 k)
        int r = (n0 & 255) + nn;            // row within 256-row tile
        int kt = (k0 >> 5) + (oct >> 2);    // k-tile
        int kk = (oct & 3) * 8;             // k within tile
        f16x8 hv;
#pragma unroll
        for (int j = 0; j < 8; ++j) hv[j] = (_Float16)t[oct * 8 + j][nn];
        size_t base = ((size_t)tn * 32 + (size_t)kt) * 16384;
        int addr = ((r << 6) + (kk << 1)) ^ ((r & 7) << 4);
        *(f16x8*)(Bf + base + addr) = hv;   // 16B store
    }
}

// ---------------- GEMM: 256x256 block, 8 waves, BK=32, 3-buffer pipeline ----------------
#define GLL16(g, l)                                                           \
    __builtin_amdgcn_global_load_lds(                                         \
        (const __attribute__((address_space(1))) void*)(g),                   \
        (__attribute__((address_space(3))) void*)(l), 16, 0, 0)

__global__ __launch_bounds__(512, 2) void gemm_kernel(
        const char* __restrict__ Ah, const char* __restrict__ Bf,
        float* __restrict__ C) {
    __shared__ char lds[98304];   // 3 x (A 16KB + B 16KB)
    const int tid  = threadIdx.x;
    const int lane = tid & 63;
    const int wid  = tid >> 6;
    const int wm = wid >> 2, wn = wid & 3;     // 2x4 waves -> 128x64 out each
    const int fr   = lane & 15;
    const int colb = (lane >> 4) << 4;         // byte offset of lane's 8-f16 k-group

    // XCD-aware swizzle: 256 wgs, 8 XCDs, 32/xcd; consecutive-on-XCD share A panels
    int wg  = blockIdx.x;
    int swz = (wg & 7) * 32 + (wg >> 3);
    int by = swz >> 4, bx = swz & 15;

    const char* pA = Ah + (size_t)by * 32 * 16384;
    const char* pB = Bf + (size_t)bx * 32 * 16384;

    int aAddr[8], bAddr[4];
#pragma unroll
    for (int m = 0; m < 8; ++m) {
        int r = wm * 128 + m * 16 + fr;
        aAddr[m] = ((r << 6) + colb) ^ ((r & 7) << 4);
    }
#pragma unroll
    for (int n = 0; n < 4; ++n) {
        int r = wn * 64 + n * 16 + fr;
        bAddr[n] = ((r << 6) + colb) ^ ((r & 7) << 4);
    }

    const int so = tid << 4;   // 0..8191, 16B per thread

    // prologue: stage tiles 0 and 1 (depth 2)
#pragma unroll
    for (int t = 0; t < 2; ++t) {
        char* d = lds + t * 32768;
        const char* sA = pA + t * 16384;
        const char* sB = pB + t * 16384;
        GLL16(sA + so, d + so);
        GLL16(sA + 8192 + so, d + 8192 + so);
        GLL16(sB + so, d + 16384 + so);
        GLL16(sB + 8192 + so, d + 24576 + so);
    }

    f32x4 acc[8][4];
#pragma unroll
    for (int m = 0; m < 8; ++m)
#pragma unroll
        for (int n = 0; n < 4; ++n)
            acc[m][n] = (f32x4){0.f, 0.f, 0.f, 0.f};

    for (int t = 0; t < 32; ++t) {
        // own tile-t chunks landed (<=4 outstanding = tile t+1's), then all waves' visible
        asm volatile("s_waitcnt vmcnt(4)" ::: "memory");
        __builtin_amdgcn_s_barrier();
        __builtin_amdgcn_sched_barrier(0);   // pin ds_reads below the barrier

        // stage tile t+2 into buf[(t+2)%3] (free: last read at body t-1, barrier-sep).
        // Wrap index past the end: stages dead-but-valid data, keeps vmcnt(4) exact.
        int t2 = (t + 2) & 31;
        char* d2 = lds + ((t + 2) % 3) * 32768;
        const char* sA = pA + t2 * 16384;
        const char* sB = pB + t2 * 16384;
        GLL16(sA + so, d2 + so);
        GLL16(sA + 8192 + so, d2 + 8192 + so);
        GLL16(sB + so, d2 + 16384 + so);
        GLL16(sB + 8192 + so, d2 + 24576 + so);

        // compute tile t
        const char* bufA = lds + (t % 3) * 32768;
        const char* bufB = bufA + 16384;
        f16x8 aH[8], bF[4];
#pragma unroll
        for (int m = 0; m < 8; ++m) aH[m] = *(const f16x8*)(bufA + aAddr[m]);
#pragma unroll
        for (int n = 0; n < 4; ++n) bF[n] = *(const f16x8*)(bufB + bAddr[n]);

        __builtin_amdgcn_s_setprio(1);
#pragma unroll
        for (int m = 0; m < 8; ++m)
#pragma unroll
            for (int n = 0; n < 4; ++n)
                acc[m][n] = __builtin_amdgcn_mfma_f32_16x16x32_f16(aH[m], bF[n], acc[m][n], 0, 0, 0);
        __builtin_amdgcn_s_setprio(0);
    }

    // epilogue: C/D layout col = lane&15, row = (lane>>4)*4 + j  (m91-verified)
    const int crow0 = by * 256 + wm * 128 + ((lane >> 4) << 2);
    const int ccol0 = bx * 256 + wn * 64 + fr;
#pragma unroll
    for (int m = 0; m < 8; ++m)
#pragma unroll
        for (int n = 0; n < 4; ++n) {
            size_t base = (size_t)(crow0 + m * 16) * N_DIM + (size_t)(ccol0 + n * 16);
#pragma unroll
            for (int j = 0; j < 4; ++j)
                C[base + (size_t)j * N_DIM] = acc[m][n][j];
        }
}

extern "C" void kernel_launch(void* const* d_in, const int* in_sizes, int n_in,
                              void* d_out, int out_size, void* d_ws, size_t ws_size,
                              hipStream_t stream) {
    const float* x      = (const float*)d_in[0];   // [4096,1024]
    const float* W      = (const float*)d_in[1];   // [1024,4096]
    const float* phases = (const float*)d_in[2];   // [1024,12]
    float* out = (float*)d_out;                    // [4096,4096] f32

    char* ws = (char*)d_ws;
    float* pm = (float*)ws;                               // 4 KB
    char* Ah = ws + 65536;                                // 8 MB
    char* Bf = Ah + (size_t)8 * 1024 * 1024;              // 8 MB
    // total ws use: 64 KB + 16 MB

    pm_kernel<<<4, 256, 0, stream>>>(phases, pm);
    asplit_kernel<<<(B_DIM * (K_DIM / 8)) / 256, 256, 0, stream>>>(x, pm, Ah);
    wsplit_kernel<<<dim3(N_DIM / 64, K_DIM / 64), 256, 0, stream>>>(W, Bf);
    gemm_kernel<<<256, 512, 0, stream>>>(Ah, Bf, out);
}

// Round 5
// 131.908 us; speedup vs baseline: 1.3781x; 1.0243x over previous
//
#include <hip/hip_runtime.h>
#include <hip/hip_bf16.h>

// out[b,n] = sum_k cos(x[b,k] * mean(phases[k,:])) * W[k,n]
// B = 4096, K = 1024, N = 4096, NQ = 12. All fp32 in/out.
//
// Round 5: single-term f16 GEMM on the 8-phase 256x256 deep-pipelined template.
// BK=64, 2x64KB LDS dbuf, 8 waves (2Mx4N, 128x64/wave). K-tile = 4 chunks
// (A-k0, B-k0, A-k1, B-k1; 16KB each). Per phase: ds_read frags -> 2 GLL
// (stage 1 chunk of next tile) -> [vmcnt(4) odd phases] -> barrier ->
// setprio+16 MFMA -> barrier. vmcnt never drains to 0 in the loop.

#define K_DIM 1024
#define N_DIM 4096
#define B_DIM 4096
#define NQ 12

typedef __attribute__((ext_vector_type(8))) _Float16 f16x8;
typedef __attribute__((ext_vector_type(4))) float f32x4;

// Global operand layout (A and B^T identical): per (row-tile tr of 256, k-tile
// kt of 64): 32KB block at ((tr*16)+kt)*32768, split into two 16KB k-half
// chunks. Within chunk, element (r, kk) r in [0,256), kk in [0,32):
//   byte = ((r<<6) + (kk<<1)) ^ ((r&7)<<4)     (bijective, 16B-aligned units)

// ---------------- phase mean ----------------
__global__ void pm_kernel(const float* __restrict__ phases, float* __restrict__ pm) {
    int j = blockIdx.x * 256 + threadIdx.x;
    if (j < K_DIM) {
        float s = 0.f;
#pragma unroll
        for (int q = 0; q < NQ; ++q) s += phases[j * NQ + q];
        pm[j] = s * (1.0f / NQ);
    }
}

// ---------------- A producer: coef = cos(x*pm) -> f16, chunked+swizzled ----------------
__global__ void asplit_kernel(const float* __restrict__ x, const float* __restrict__ pm,
                              char* __restrict__ Ah) {
    int i = blockIdx.x * 256 + threadIdx.x;    // one thread per 8 consecutive k
    int row = i >> 7;                          // 0..4095  (128 threads per row)
    int k0  = (i & 127) << 3;                  // 0..1016
    const float* xp = x + ((size_t)row << 10) + k0;
    float4 xa = *(const float4*)xp;
    float4 xb = *(const float4*)(xp + 4);
    float4 pa = *(const float4*)(pm + k0);
    float4 pb = *(const float4*)(pm + k0 + 4);
    f16x8 hv;
    hv[0] = (_Float16)__cosf(xa.x * pa.x); hv[1] = (_Float16)__cosf(xa.y * pa.y);
    hv[2] = (_Float16)__cosf(xa.z * pa.z); hv[3] = (_Float16)__cosf(xa.w * pa.w);
    hv[4] = (_Float16)__cosf(xb.x * pb.x); hv[5] = (_Float16)__cosf(xb.y * pb.y);
    hv[6] = (_Float16)__cosf(xb.z * pb.z); hv[7] = (_Float16)__cosf(xb.w * pb.w);
    int tr = row >> 8, kt = k0 >> 6, khalf = (k0 & 63) >> 5;
    int r = row & 255, kk = k0 & 31;
    size_t base = ((size_t)tr * 16 + (size_t)kt) * 32768 + (size_t)khalf * 16384;
    int addr = ((r << 6) + (kk << 1)) ^ ((r & 7) << 4);   // 16B aligned
    *(f16x8*)(Ah + base + addr) = hv;
}

// ---------------- W producer: transpose [K][N] -> [N][K] f16, chunked+swizzled ----------------
__global__ void wsplit_kernel(const float* __restrict__ W, char* __restrict__ Bf) {
    __shared__ float t[64][65];
    int n0 = blockIdx.x * 64, k0 = blockIdx.y * 64;
    int tid = threadIdx.x;
#pragma unroll
    for (int p = 0; p < 16; ++p) {
        int lin = p * 256 + tid;
        int kk = lin >> 6, nn = lin & 63;
        t[kk][nn] = W[(size_t)(k0 + kk) * N_DIM + n0 + nn];   // coalesced in n
    }
    __syncthreads();
    int tr = n0 >> 8, kt = k0 >> 6;
    size_t tbase = ((size_t)tr * 16 + (size_t)kt) * 32768;
#pragma unroll
    for (int p2 = 0; p2 < 2; ++p2) {
        int w = p2 * 256 + tid;
        int nn = w >> 3, oct = w & 7;       // 64 n-rows x 8 k-octets (of 64 k)
        int r = (n0 & 255) + nn;            // row within 256-row tile
        int khalf = oct >> 2;               // k-half chunk
        int kk = (oct & 3) * 8;             // k within chunk
        f16x8 hv;
#pragma unroll
        for (int j = 0; j < 8; ++j) hv[j] = (_Float16)t[oct * 8 + j][nn];
        int addr = ((r << 6) + (kk << 1)) ^ ((r & 7) << 4);
        *(f16x8*)(Bf + tbase + (size_t)khalf * 16384 + addr) = hv;
    }
}

// ---------------- GEMM: 256x256 block, 8 waves, BK=64, 8-phase pipeline ----------------
#define GLL16(g, l)                                                           \
    __builtin_amdgcn_global_load_lds(                                         \
        (const __attribute__((address_space(1))) void*)(g),                   \
        (__attribute__((address_space(3))) void*)(l), 16, 0, 0)

__global__ __launch_bounds__(512, 2) void gemm_kernel(
        const char* __restrict__ Ah, const char* __restrict__ Bf,
        float* __restrict__ C) {
    __shared__ char lds[131072];   // 2 buffers x (A-k0 | B-k0 | A-k1 | B-k1), 16KB each
    const int tid  = threadIdx.x;
    const int lane = tid & 63;
    const int wid  = tid >> 6;
    const int wm = wid >> 2, wn = wid & 3;     // 2x4 waves -> 128x64 out each
    const int fr   = lane & 15;
    const int colb = (lane >> 4) << 4;         // byte offset of lane's 8-f16 k-group

    // XCD-aware swizzle: 256 wgs, 8 XCDs, 32/XCD (bijective since 256%8==0)
    int wg  = blockIdx.x;
    int swz = (wg & 7) * 32 + (wg >> 3);
    const int by = swz >> 4, bx = swz & 15;

    const char* pA = Ah + (size_t)by * 16 * 32768;
    const char* pB = Bf + (size_t)bx * 16 * 32768;

    // within-chunk fragment offsets
    int aOff[8], bOff[4];
#pragma unroll
    for (int m = 0; m < 8; ++m) {
        int r = wm * 128 + m * 16 + fr;
        aOff[m] = ((r << 6) + colb) ^ ((r & 7) << 4);
    }
#pragma unroll
    for (int n = 0; n < 4; ++n) {
        int r = wn * 64 + n * 16 + fr;
        bOff[n] = ((r << 6) + colb) ^ ((r & 7) << 4);
    }

    const int so = tid << 4;   // 0..8191

    // prologue: stage tile 0 (4 chunks) into buf0, publish chunks 0,1
#pragma unroll
    for (int c = 0; c < 4; ++c) {
        const char* s = ((c & 1) ? pB : pA) + (c >> 1) * 16384;
        char* d = lds + c * 16384;
        GLL16(s + so, d + so);
        GLL16(s + 8192 + so, d + 8192 + so);
    }
    asm volatile("s_waitcnt vmcnt(4)" ::: "memory");   // chunks 0,1 resident
    __builtin_amdgcn_s_barrier();

    f32x4 acc[8][4];
#pragma unroll
    for (int m = 0; m < 8; ++m)
#pragma unroll
        for (int n = 0; n < 4; ++n)
            acc[m][n] = (f32x4){0.f, 0.f, 0.f, 0.f};

    for (int t = 0; t < 16; ++t) {
        const int cur = t & 1;
        const char* bufc = lds + cur * 65536;
        char* bufn = lds + (cur ^ 1) * 65536;
        const char* srcA = pA + (size_t)((t + 1) & 15) * 32768;   // wrap: dead-stage at t=15
        const char* srcB = pB + (size_t)((t + 1) & 15) * 32768;

#pragma unroll
        for (int kh = 0; kh < 2; ++kh) {
            f16x8 bF[4];
#pragma unroll
            for (int mh = 0; mh < 2; ++mh) {
                // ---- phase (kh, mh):  chunk c = kh*2 + mh of NEXT tile staged ----
                // 1. ds_read this phase's fragments (published by prior barrier)
                if (mh == 0) {
#pragma unroll
                    for (int n = 0; n < 4; ++n)
                        bF[n] = *(const f16x8*)(bufc + 16384 + kh * 32768 + bOff[n]);
                }
                f16x8 aH[4];
#pragma unroll
                for (int q = 0; q < 4; ++q)
                    aH[q] = *(const f16x8*)(bufc + kh * 32768 + aOff[mh * 4 + q]);

                // 2. stage one chunk of tile t+1 into the other buffer
                {
                    const int c = kh * 2 + mh;
                    const char* s = ((c & 1) ? srcB : srcA) + (c >> 1) * 16384;
                    char* d = bufn + c * 16384;
                    GLL16(s + so, d + so);
                    GLL16(s + 8192 + so, d + 8192 + so);
                }

                // 3. counted vmcnt on odd phases (publishes the 2 chunks needed
                //    by the NEXT phase-pair; 2 chunk-stages = 4 loads stay in flight)
                if (mh == 1)
                    asm volatile("s_waitcnt vmcnt(4)" ::: "memory");

                // 4. barrier A: all waves' vmcnt passed -> staged chunks visible
                __builtin_amdgcn_s_barrier();

                // 5. MFMA quadrant (compiler inserts lgkm waits for aH/bF)
                __builtin_amdgcn_s_setprio(1);
#pragma unroll
                for (int q = 0; q < 4; ++q)
#pragma unroll
                    for (int n = 0; n < 4; ++n)
                        acc[mh * 4 + q][n] = __builtin_amdgcn_mfma_f32_16x16x32_f16(
                            aH[q], bF[n], acc[mh * 4 + q][n], 0, 0, 0);
                __builtin_amdgcn_s_setprio(0);

                // 6. barrier B: this phase's LDS reads complete before next
                //    phase's GLL can touch the buffers
                __builtin_amdgcn_s_barrier();
            }
        }
    }

    // epilogue: C/D layout col = lane&15, row = (lane>>4)*4 + j  (m91-verified)
    const int crow0 = by * 256 + wm * 128 + ((lane >> 4) << 2);
    const int ccol0 = bx * 256 + wn * 64 + fr;
#pragma unroll
    for (int m = 0; m < 8; ++m)
#pragma unroll
        for (int n = 0; n < 4; ++n) {
            size_t base = (size_t)(crow0 + m * 16) * N_DIM + (size_t)(ccol0 + n * 16);
#pragma unroll
            for (int j = 0; j < 4; ++j)
                C[base + (size_t)j * N_DIM] = acc[m][n][j];
        }
}

extern "C" void kernel_launch(void* const* d_in, const int* in_sizes, int n_in,
                              void* d_out, int out_size, void* d_ws, size_t ws_size,
                              hipStream_t stream) {
    const float* x      = (const float*)d_in[0];   // [4096,1024]
    const float* W      = (const float*)d_in[1];   // [1024,4096]
    const float* phases = (const float*)d_in[2];   // [1024,12]
    float* out = (float*)d_out;                    // [4096,4096] f32

    char* ws = (char*)d_ws;
    float* pm = (float*)ws;                               // 4 KB
    char* Ah = ws + 65536;                                // 8 MB
    char* Bf = Ah + (size_t)8 * 1024 * 1024;              // 8 MB
    // total ws use: 64 KB + 16 MB

    pm_kernel<<<4, 256, 0, stream>>>(phases, pm);
    asplit_kernel<<<(B_DIM * (K_DIM / 8)) / 256, 256, 0, stream>>>(x, pm, Ah);
    wsplit_kernel<<<dim3(N_DIM / 64, K_DIM / 64), 256, 0, stream>>>(W, Bf);
    gemm_kernel<<<256, 512, 0, stream>>>(Ah, Bf, out);
}

// Round 6
// 131.660 us; speedup vs baseline: 1.3807x; 1.0019x over previous
//
#include <hip/hip_runtime.h>
#include <hip/hip_bf16.h>

// out[b,n] = sum_k cos(x[b,k] * mean(phases[k,:])) * W[k,n]
// B = 4096, K = 1024, N = 4096, NQ = 12. All fp32 in/out.
//
// Round 6: single-term f16. Block 256(M)x128(N), 4 waves stacked along M
// (wave owns 64x128). A staged via global_load_lds into 2x32KB LDS dbuf
// (8 ds_read_b128/wave/K-tile, zero redundancy); B fragments read DIRECTLY
// from global (coalesced 1KB wave-windows, L2/L3-resident) -> LDS-unit time
// ~1536 cyc/CU/K-tile < MFMA 2483 cyc -> MFMA-bound. Proven __syncthreads
// dbuf schedule: sync -> B-loads -> GLL(t+1) -> compute(t) -> sync.

#define K_DIM 1024
#define N_DIM 4096
#define B_DIM 4096
#define NQ 12

typedef __attribute__((ext_vector_type(8))) _Float16 f16x8;
typedef __attribute__((ext_vector_type(4))) float f32x4;

// Operand layout (A and B^T identical): per (row-tile tr of 256, k-tile kt of
// 64): 32KB block at ((tr*16)+kt)*32768, two 16KB k-half chunks. Within chunk,
// element (r, kk), r in [0,256), kk in [0,32):
//   byte = (((r<<6) + (kk<<1)) ^ ((r&7)<<4))    (bijective, 16B-granular)

// ---------------- phase mean ----------------
__global__ void pm_kernel(const float* __restrict__ phases, float* __restrict__ pm) {
    int j = blockIdx.x * 256 + threadIdx.x;
    if (j < K_DIM) {
        float s = 0.f;
#pragma unroll
        for (int q = 0; q < NQ; ++q) s += phases[j * NQ + q];
        pm[j] = s * (1.0f / NQ);
    }
}

// ---------------- A producer: coef = cos(x*pm) -> f16, chunked+swizzled ----------------
__global__ void asplit_kernel(const float* __restrict__ x, const float* __restrict__ pm,
                              char* __restrict__ Ah) {
    int i = blockIdx.x * 256 + threadIdx.x;    // one thread per 8 consecutive k
    int row = i >> 7;                          // 0..4095  (128 threads per row)
    int k0  = (i & 127) << 3;                  // 0..1016
    const float* xp = x + ((size_t)row << 10) + k0;
    float4 xa = *(const float4*)xp;
    float4 xb = *(const float4*)(xp + 4);
    float4 pa = *(const float4*)(pm + k0);
    float4 pb = *(const float4*)(pm + k0 + 4);
    f16x8 hv;
    hv[0] = (_Float16)__cosf(xa.x * pa.x); hv[1] = (_Float16)__cosf(xa.y * pa.y);
    hv[2] = (_Float16)__cosf(xa.z * pa.z); hv[3] = (_Float16)__cosf(xa.w * pa.w);
    hv[4] = (_Float16)__cosf(xb.x * pb.x); hv[5] = (_Float16)__cosf(xb.y * pb.y);
    hv[6] = (_Float16)__cosf(xb.z * pb.z); hv[7] = (_Float16)__cosf(xb.w * pb.w);
    int tr = row >> 8, kt = k0 >> 6, khalf = (k0 & 63) >> 5;
    int r = row & 255, kk = k0 & 31;
    size_t base = ((size_t)tr * 16 + (size_t)kt) * 32768 + (size_t)khalf * 16384;
    int addr = ((r << 6) + (kk << 1)) ^ ((r & 7) << 4);   // 16B aligned
    *(f16x8*)(Ah + base + addr) = hv;
}

// ---------------- W producer: transpose [K][N] -> [N][K] f16, chunked+swizzled ----------------
__global__ void wsplit_kernel(const float* __restrict__ W, char* __restrict__ Bf) {
    __shared__ float t[64][65];
    int n0 = blockIdx.x * 64, k0 = blockIdx.y * 64;
    int tid = threadIdx.x;
#pragma unroll
    for (int p = 0; p < 16; ++p) {
        int lin = p * 256 + tid;
        int kk = lin >> 6, nn = lin & 63;
        t[kk][nn] = W[(size_t)(k0 + kk) * N_DIM + n0 + nn];   // coalesced in n
    }
    __syncthreads();
    int tr = n0 >> 8, kt = k0 >> 6;
    size_t tbase = ((size_t)tr * 16 + (size_t)kt) * 32768;
#pragma unroll
    for (int p2 = 0; p2 < 2; ++p2) {
        int w = p2 * 256 + tid;
        int nn = w >> 3, oct = w & 7;       // 64 n-rows x 8 k-octets (of 64 k)
        int r = (n0 & 255) + nn;            // row within 256-row tile
        int khalf = oct >> 2;               // k-half chunk
        int kk = (oct & 3) * 8;             // k within chunk
        f16x8 hv;
#pragma unroll
        for (int j = 0; j < 8; ++j) hv[j] = (_Float16)t[oct * 8 + j][nn];
        int addr = ((r << 6) + (kk << 1)) ^ ((r & 7) << 4);
        *(f16x8*)(Bf + tbase + (size_t)khalf * 16384 + addr) = hv;
    }
}

// ---------------- GEMM: 256x128 block, 4 waves (4Mx1N), A-LDS + B-global ----------------
#define GLL16(g, l)                                                           \
    __builtin_amdgcn_global_load_lds(                                         \
        (const __attribute__((address_space(1))) void*)(g),                   \
        (__attribute__((address_space(3))) void*)(l), 16, 0, 0)

__global__ __launch_bounds__(256, 2) void gemm_kernel(
        const char* __restrict__ Ah, const char* __restrict__ Bf,
        float* __restrict__ C) {
    __shared__ char lds[65536];   // 2 x 32KB A-tile buffers (swizzled images)
    const int tid  = threadIdx.x;
    const int lane = tid & 63;
    const int wid  = tid >> 6;                 // wave owns rows wid*64..+63, all 128 cols
    const int fr   = lane & 15;
    const int colb = (lane >> 4) << 4;         // byte offset of lane's 8-f16 k-group

    // XCD-aware swizzle: 512 wgs, 8 XCDs, 64/XCD (bijective since 512%8==0).
    // Consecutive-on-XCD blocks share the A row-panel (same by).
    int wg  = blockIdx.x;
    int swz = (wg & 7) * 64 + (wg >> 3);
    const int by = swz >> 5;        // 0..15  (M tiles of 256)
    const int bx = swz & 31;        // 0..31  (N tiles of 128)

    const char* pA = Ah + (size_t)by * 16 * 32768;
    const char* pB = Bf + (size_t)(bx >> 1) * 16 * 32768;   // 256-row B^T tile
    const int rB = (bx & 1) * 128;                           // our 128-row half

    // A fragment offsets within a 32KB LDS buffer: m=0..3, khalf=0..1
    int aOff[2][4];
#pragma unroll
    for (int kh = 0; kh < 2; ++kh)
#pragma unroll
        for (int m = 0; m < 4; ++m) {
            int r = wid * 64 + m * 16 + fr;
            aOff[kh][m] = kh * 16384 + ((((r << 6) + colb)) ^ ((r & 7) << 4));
        }
    // B fragment offsets within a 32KB global chunk: n=0..7, khalf=0..1
    int bOff[2][8];
#pragma unroll
    for (int kh = 0; kh < 2; ++kh)
#pragma unroll
        for (int n = 0; n < 8; ++n) {
            int r = rB + n * 16 + fr;
            bOff[kh][n] = kh * 16384 + ((((r << 6) + colb)) ^ ((r & 7) << 4));
        }

    const int so = tid << 4;   // 0..4095 (256 threads x 16B)

    // prologue: stage A tile 0 into buf0 (32KB = 8 GLL16/thread)
#pragma unroll
    for (int p = 0; p < 8; ++p)
        GLL16(pA + p * 4096 + so, lds + p * 4096 + so);

    f32x4 acc[4][8];
#pragma unroll
    for (int m = 0; m < 4; ++m)
#pragma unroll
        for (int n = 0; n < 8; ++n)
            acc[m][n] = (f32x4){0.f, 0.f, 0.f, 0.f};

    int cur = 0;
    for (int t = 0; t < 16; ++t) {
        __syncthreads();   // buf[cur] = tile t resident & visible (drains vmcnt)

        // 1. B fragment loads for tile t, issued FIRST (oldest): waiting on
        //    them later leaves the younger GLLs in flight.
        const char* bChunk = pB + (size_t)t * 32768;
        f16x8 bF[2][8];
#pragma unroll
        for (int kh = 0; kh < 2; ++kh)
#pragma unroll
            for (int n = 0; n < 8; ++n)
                bF[kh][n] = *(const f16x8*)(bChunk + bOff[kh][n]);

        // 2. stage A tile t+1 into the other buffer (overlaps with compute;
        //    drained by the loop-end sync). Wrap at t=15: dead-but-valid.
        {
            const char* sA = pA + (size_t)((t + 1) & 15) * 32768;
            char* d = lds + (cur ^ 1) * 32768;
#pragma unroll
            for (int p = 0; p < 8; ++p)
                GLL16(sA + p * 4096 + so, d + p * 4096 + so);
        }

        // 3. compute tile t from buf[cur]
        const char* bufA = lds + cur * 32768;
#pragma unroll
        for (int kh = 0; kh < 2; ++kh) {
            f16x8 aH[4];
#pragma unroll
            for (int m = 0; m < 4; ++m)
                aH[m] = *(const f16x8*)(bufA + aOff[kh][m]);
            __builtin_amdgcn_s_setprio(1);
#pragma unroll
            for (int m = 0; m < 4; ++m)
#pragma unroll
                for (int n = 0; n < 8; ++n)
                    acc[m][n] = __builtin_amdgcn_mfma_f32_16x16x32_f16(
                        aH[m], bF[kh][n], acc[m][n], 0, 0, 0);
            __builtin_amdgcn_s_setprio(0);
        }

        __syncthreads();   // all reads of buf[cur] done; t+1 stage drained
        cur ^= 1;
    }

    // epilogue: C/D layout col = lane&15, row = (lane>>4)*4 + j  (m91-verified)
    const int crow0 = by * 256 + wid * 64 + ((lane >> 4) << 2);
    const int ccol0 = bx * 128 + fr;
#pragma unroll
    for (int m = 0; m < 4; ++m)
#pragma unroll
        for (int n = 0; n < 8; ++n) {
            size_t base = (size_t)(crow0 + m * 16) * N_DIM + (size_t)(ccol0 + n * 16);
#pragma unroll
            for (int j = 0; j < 4; ++j)
                C[base + (size_t)j * N_DIM] = acc[m][n][j];
        }
}

extern "C" void kernel_launch(void* const* d_in, const int* in_sizes, int n_in,
                              void* d_out, int out_size, void* d_ws, size_t ws_size,
                              hipStream_t stream) {
    const float* x      = (const float*)d_in[0];   // [4096,1024]
    const float* W      = (const float*)d_in[1];   // [1024,4096]
    const float* phases = (const float*)d_in[2];   // [1024,12]
    float* out = (float*)d_out;                    // [4096,4096] f32

    char* ws = (char*)d_ws;
    float* pm = (float*)ws;                               // 4 KB
    char* Ah = ws + 65536;                                // 8 MB
    char* Bf = Ah + (size_t)8 * 1024 * 1024;              // 8 MB
    // total ws use: 64 KB + 16 MB

    pm_kernel<<<4, 256, 0, stream>>>(phases, pm);
    asplit_kernel<<<(B_DIM * (K_DIM / 8)) / 256, 256, 0, stream>>>(x, pm, Ah);
    wsplit_kernel<<<dim3(N_DIM / 64, K_DIM / 64), 256, 0, stream>>>(W, Bf);
    gemm_kernel<<<512, 256, 0, stream>>>(Ah, Bf, out);
}